// Round 5
// baseline (916.599 us; speedup 1.0000x reference)
//
#include <hip/hip_runtime.h>
#include <stdint.h>

#define N_NODES 50000
#define M_PAD   50048   // 391*128
#define R_REL   8
#define E_EDGES 100000
#define D_IN    768
#define D_H     256
#define N_CAT   2304    // 9*256 : [self | rel0..rel7]
#define K1      2304    // layer-1 GEMM K : [h | 8 rel-means]
#define LN_EPS  1e-5f

#define TILES_M 391     // M_PAD/128
#define NCHUNK  49      // ceil(50000/1024)
#define E_PAD_MAX 960000 // 800k edges + <=150k pad slots

typedef __attribute__((ext_vector_type(8))) __bf16        bf16x8;
typedef __attribute__((ext_vector_type(4))) float         f32x4;
typedef __attribute__((ext_vector_type(8))) unsigned short u16x8;
typedef __attribute__((ext_vector_type(4))) unsigned short u16x4;
typedef __attribute__((ext_vector_type(4))) int            i32x4;

__device__ __forceinline__ float bf2f(unsigned short u) {
  union { float f; uint32_t i; } c; c.i = ((uint32_t)u) << 16; return c.f;
}
__device__ __forceinline__ unsigned short f2bf(float f) {
  uint32_t x = __float_as_uint(f);
  uint32_t r = (x + 0x7fffu + ((x >> 16) & 1u)) >> 16;   // RNE
  return (unsigned short)r;
}

__device__ __forceinline__ void gload_lds16(const void* g, uint32_t lds_off) {
  __builtin_amdgcn_global_load_lds(
      (const __attribute__((address_space(1))) void*)(uintptr_t)g,
      (__attribute__((address_space(3))) void*)(uintptr_t)lds_off, 16, 0, 0);
}

// ---------------- CSR build (node-major, rel-grouped within node) ----------------
__global__ void k_deg(const int* __restrict__ tgt, int* __restrict__ deg) {
  int e = blockIdx.x * 256 + threadIdx.x;
  if (e >= R_REL * E_EDGES) return;
  int r = e / E_EDGES;
  atomicAdd(&deg[r * N_NODES + tgt[e]], 1);
}

__global__ void k_ndeg(const int* __restrict__ deg, int* __restrict__ pdeg) {
  int t = blockIdx.x * 256 + threadIdx.x;
  if (t >= N_NODES) return;
  int s = 0;
#pragma unroll
  for (int r = 0; r < R_REL; ++r) s += deg[r * N_NODES + t];
  pdeg[t] = (s + 3) & ~3;
}

__global__ __launch_bounds__(256)
void k_scan1(const int* __restrict__ deg, int* __restrict__ rowptr,
             int* __restrict__ bsum) {
  __shared__ int wtot[4];
  const int chunk = blockIdx.x, tid = threadIdx.x;
  const int wave = tid >> 6, lane = tid & 63;
  const int i0 = chunk * 1024 + tid * 4;
  int v0 = 0, v1 = 0, v2 = 0, v3 = 0;
  const int* d = deg;
  if (chunk != NCHUNK - 1) {
    i32x4 v = *(const i32x4*)(d + i0);
    v0 = v[0]; v1 = v[1]; v2 = v[2]; v3 = v[3];
  } else {
    if (i0 + 0 < N_NODES) v0 = d[i0 + 0];
    if (i0 + 1 < N_NODES) v1 = d[i0 + 1];
    if (i0 + 2 < N_NODES) v2 = d[i0 + 2];
    if (i0 + 3 < N_NODES) v3 = d[i0 + 3];
  }
  const int tsum = v0 + v1 + v2 + v3;
  int inc = tsum;
#pragma unroll
  for (int off = 1; off < 64; off <<= 1) {
    int t = __shfl_up(inc, off, 64);
    if (lane >= off) inc += t;
  }
  if (lane == 63) wtot[wave] = inc;
  __syncthreads();
  int woff = 0;
#pragma unroll
  for (int w = 0; w < 4; ++w) woff += (w < wave) ? wtot[w] : 0;
  int excl = woff + inc - tsum;
  int* rp = rowptr;
  if (i0 + 0 < N_NODES) rp[i0 + 0] = excl;
  if (i0 + 1 < N_NODES) rp[i0 + 1] = excl + v0;
  if (i0 + 2 < N_NODES) rp[i0 + 2] = excl + v0 + v1;
  if (i0 + 3 < N_NODES) rp[i0 + 3] = excl + v0 + v1 + v2;
  if (tid == 0) bsum[chunk] = wtot[0] + wtot[1] + wtot[2] + wtot[3];
}

__global__ __launch_bounds__(64)
void k_scan2(const int* __restrict__ bsum, int* __restrict__ chunkoff,
             int* __restrict__ rowptr) {
  const int lane = threadIdx.x & 63;
  int v = (lane < NCHUNK) ? bsum[lane] : 0;
  int inc = v;
#pragma unroll
  for (int off = 1; off < 64; off <<= 1) {
    int t = __shfl_up(inc, off, 64);
    if (lane >= off) inc += t;
  }
  if (lane < NCHUNK) chunkoff[lane] = inc - v;   // exclusive
  if (lane == NCHUNK - 1) rowptr[N_NODES] = inc;
}

__global__ __launch_bounds__(256)
void k_scan3(const int* __restrict__ chunkoff, int* __restrict__ rowptr) {
  const int chunk = blockIdx.x;
  if (chunk == 0) return;
  const int off = chunkoff[chunk];
  const int i0 = chunk * 1024 + threadIdx.x * 4;
#pragma unroll
  for (int j = 0; j < 4; ++j)
    if (i0 + j < N_NODES) rowptr[i0 + j] += off;
}

// per-node {start, padded_count} for the flat gather
__global__ void k_prep(const int* __restrict__ nodeptr, int2* __restrict__ scN) {
  int t = blockIdx.x * 256 + threadIdx.x;
  if (t >= N_NODES) return;
  scN[t] = make_int2(nodeptr[t], nodeptr[t + 1] - nodeptr[t]);
}

// per-(node,rel) {global start, count} (rel groups contiguous within node)
__global__ void k_prep8(const int* __restrict__ nodeptr, const int* __restrict__ deg,
                        int2* __restrict__ sc8) {
  int id = blockIdx.x * 256 + threadIdx.x;
  if (id >= N_NODES * 8) return;
  int t = id >> 3, r = id & 7;
  int base = nodeptr[t];
  for (int rr = 0; rr < r; ++rr) base += deg[rr * N_NODES + t];
  sc8[id] = make_int2(base, deg[r * N_NODES + t]);
}

// fill rel-grouped adjacency: e2[slot] = {src | rel<<16, nw[src]/deg[rel][tgt]}
__global__ void k_fill(const int* __restrict__ src, const int* __restrict__ tgt,
                       const float* __restrict__ nw, const int2* __restrict__ sc8,
                       const int* __restrict__ deg, int* __restrict__ cursor8,
                       int2* __restrict__ e2) {
  int e = blockIdx.x * 256 + threadIdx.x;
  if (e >= R_REL * E_EDGES) return;
  int r = e / E_EDGES;
  int t = tgt[e], s = src[e];
  int pos = atomicAdd(&cursor8[t * 8 + r], 1);
  int slot = sc8[t * 8 + r].x + pos;
  float w = nw[s] / (float)deg[r * N_NODES + t];
  e2[slot] = make_int2(s | (r << 16), __float_as_int(w));
}

// ---------------- conversions ----------------
__global__ void k_cvt_x(const float* __restrict__ x, unsigned short* __restrict__ xb) {
  const size_t i = ((size_t)blockIdx.x * 256 + threadIdx.x) * 4;
  if (i >= (size_t)N_NODES * D_IN) return;
  const f32x4 v = *(const f32x4*)(x + i);
  u16x4 o = { f2bf(v[0]), f2bf(v[1]), f2bf(v[2]), f2bf(v[3]) };
  *(u16x4*)(xb + i) = o;
}

// Wt0[n][k] = n<256 ? Ws0[k][n] : Wr0[(n-256)>>8][k][n&255]   (bf16, [N_CAT][768])
__global__ void k_cvt_w(const float* __restrict__ Ws, const float* __restrict__ Wr,
                        unsigned short* __restrict__ Wt, int K) {
  int idx = blockIdx.x * 256 + threadIdx.x;
  if (idx >= N_CAT * K) return;
  int n = idx / K, k = idx - n * K;
  float v = (n < 256) ? Ws[k * 256 + n]
                      : Wr[(size_t)((n - 256) >> 8) * K * 256 + k * 256 + (n & 255)];
  Wt[idx] = f2bf(v);
}

// Wt1b[n][k], n in [0,256), k in [0,2304): k<256 -> Ws1[k][n], else Wr1[k/256-1][k&255][n]
__global__ void k_cvt_w1(const float* __restrict__ Ws, const float* __restrict__ Wr,
                         unsigned short* __restrict__ Wt) {
  int idx = blockIdx.x * 256 + threadIdx.x;
  if (idx >= 256 * K1) return;
  int n = idx / K1, k = idx - n * K1;
  float v = (k < 256) ? Ws[k * 256 + n]
                      : Wr[(size_t)(((k >> 8) - 1) * 256 + (k & 255)) * 256 + n];
  Wt[idx] = f2bf(v);
}

// ---- swizzled epilogue (shared pattern): 32 KB LDS, stride-64 rows, group-XOR ----
// store logical (row, col): phys group = (col>>3) ^ (row&7)
#define EP_STORE(st, row, col, val) \
  (st)[(row) * 64 + ((((col) >> 3) ^ ((row) & 7)) << 3) + ((col) & 7)] = (val)

// ---------------- bf16 MFMA GEMM, BK=64 (layer 0): Y[M_PAD,N_CAT] = xb @ Wt0^T ------
__global__ __launch_bounds__(256, 2)
void k_gemm(const unsigned short* __restrict__ A, const unsigned short* __restrict__ Bt,
            unsigned short* __restrict__ C, int K) {
  const int TN = 18, TTOT = TN * TILES_M, TPX = (TTOT + 7) / 8;
  const int tile = (blockIdx.x & 7) * TPX + (blockIdx.x >> 3);
  if (tile >= TTOT) return;
  const int tileM = (tile / TN) * 128;
  const int tileN = (tile % TN) * 128;

  __shared__ __align__(16) char smem[32768];   // A 16K @0, B 16K @16384; epilogue 32K
  const int tid  = threadIdx.x;
  const int wave = tid >> 6, lane = tid & 63;
  const int wm = (wave >> 1) * 64, wn = (wave & 1) * 64;

  f32x4 acc[4][4] = {};

  const int rl = lane >> 3, sl8 = lane & 7;
  const int cch = sl8 ^ rl;                      // slot s of row r holds chunk s^(r&7)
  const int srow = wave * 8 + rl;
  const unsigned short* gA = A  + (size_t)(tileM + srow) * K + cch * 8;
  const unsigned short* gB = Bt + (size_t)(tileN + srow) * K + cch * 8;
  const uint32_t ldsA = (uint32_t)(uintptr_t)smem;
  const uint32_t ldsB = ldsA + 16384;
  const uint32_t lA0 = ldsA + (wave * 8) * 128;
  const uint32_t lB0 = ldsB + (wave * 8) * 128;

  const char* pAb = smem         + (wm + (lane & 15)) * 128;
  const char* pBb = smem + 16384 + (wn + (lane & 15)) * 128;
  const int fph = lane >> 4, x7 = lane & 7;

  const int nk = K >> 6;
  for (int kt = 0; kt < nk; ++kt) {
    const size_t koff = (size_t)kt * 64;
    __syncthreads();
#pragma unroll
    for (int j = 0; j < 4; ++j) {
      gload_lds16(gA + (size_t)j * 32 * K + koff, lA0 + j * 4096);
      gload_lds16(gB + (size_t)j * 32 * K + koff, lB0 + j * 4096);
    }
    __syncthreads();
#pragma unroll
    for (int kk = 0; kk < 2; ++kk) {
      const int sA = ((kk * 4 + fph) ^ x7) * 16;
      bf16x8 af[4], bfr[4];
#pragma unroll
      for (int i = 0; i < 4; ++i) af[i]  = *(const bf16x8*)(pAb + i * 2048 + sA);
#pragma unroll
      for (int j = 0; j < 4; ++j) bfr[j] = *(const bf16x8*)(pBb + j * 2048 + sA);
#pragma unroll
      for (int i = 0; i < 4; ++i)
#pragma unroll
        for (int j = 0; j < 4; ++j)
          acc[i][j] = __builtin_amdgcn_mfma_f32_16x16x32_bf16(af[i], bfr[j], acc[i][j], 0, 0, 0);
    }
  }

  __syncthreads();
  unsigned short* st = (unsigned short*)smem + wave * 4096;   // 64x64 u16, group-XOR
  const int rq = (lane >> 4) * 4, cq = lane & 15;
#pragma unroll
  for (int i = 0; i < 4; ++i)
#pragma unroll
    for (int j = 0; j < 4; ++j)
#pragma unroll
      for (int p = 0; p < 4; ++p)
        EP_STORE(st, i * 16 + rq + p, j * 16 + cq, f2bf(acc[i][j][p]));
#pragma unroll
  for (int pass = 0; pass < 8; ++pass) {
    const int row = pass * 8 + (lane >> 3);
    u16x8 v = *(const u16x8*)(st + row * 64 + (((lane & 7) ^ (row & 7)) << 3));
    size_t off = (size_t)(tileM + wm + row) * N_CAT + tileN + wn + (lane & 7) * 8;
    *(u16x8*)(C + off) = v;
  }
}

// ------- layer-1 GEMM, K=2304, dual-source A: cols 0:256 from h, 256:2304 from G8 ----
__global__ __launch_bounds__(256, 2)
void k_gemm2(const unsigned short* __restrict__ h, const unsigned short* __restrict__ G8,
             const unsigned short* __restrict__ Bt, unsigned short* __restrict__ C) {
  const int TTOT = 2 * TILES_M, TPX = (TTOT + 7) / 8;   // 782, 98
  const int tile = (blockIdx.x & 7) * TPX + (blockIdx.x >> 3);
  if (tile >= TTOT) return;
  const int tileM = (tile >> 1) * 128;
  const int tileN = (tile & 1) * 128;

  __shared__ __align__(16) char smem[32768];
  const int tid  = threadIdx.x;
  const int wave = tid >> 6, lane = tid & 63;
  const int wm = (wave >> 1) * 64, wn = (wave & 1) * 64;

  f32x4 acc[4][4] = {};

  const int rl = lane >> 3, sl8 = lane & 7;
  const int cch = sl8 ^ rl;
  const int srow = wave * 8 + rl;
  const unsigned short* gH = h  + (size_t)(tileM + srow) * 256  + cch * 8;
  const unsigned short* gG = G8 + (size_t)(tileM + srow) * 2048 + cch * 8;
  const unsigned short* gB = Bt + (size_t)(tileN + srow) * K1   + cch * 8;
  const uint32_t ldsA = (uint32_t)(uintptr_t)smem;
  const uint32_t ldsB = ldsA + 16384;
  const uint32_t lA0 = ldsA + (wave * 8) * 128;
  const uint32_t lB0 = ldsB + (wave * 8) * 128;

  const char* pAb = smem         + (wm + (lane & 15)) * 128;
  const char* pBb = smem + 16384 + (wn + (lane & 15)) * 128;
  const int fph = lane >> 4, x7 = lane & 7;

  for (int kt = 0; kt < (K1 >> 6); ++kt) {
    const int koff = kt * 64;
    const bool fromH = (kt < 4);
    const unsigned short* a0 = fromH ? gH + koff : gG + (koff - 256);
    const size_t astep = fromH ? (size_t)32 * 256 : (size_t)32 * 2048;
    __syncthreads();
#pragma unroll
    for (int j = 0; j < 4; ++j) {
      gload_lds16(a0 + (size_t)j * astep, lA0 + j * 4096);
      gload_lds16(gB + (size_t)j * 32 * K1 + koff, lB0 + j * 4096);
    }
    __syncthreads();
#pragma unroll
    for (int kk = 0; kk < 2; ++kk) {
      const int sA = ((kk * 4 + fph) ^ x7) * 16;
      bf16x8 af[4], bfr[4];
#pragma unroll
      for (int i = 0; i < 4; ++i) af[i]  = *(const bf16x8*)(pAb + i * 2048 + sA);
#pragma unroll
      for (int j = 0; j < 4; ++j) bfr[j] = *(const bf16x8*)(pBb + j * 2048 + sA);
#pragma unroll
      for (int i = 0; i < 4; ++i)
#pragma unroll
        for (int j = 0; j < 4; ++j)
          acc[i][j] = __builtin_amdgcn_mfma_f32_16x16x32_bf16(af[i], bfr[j], acc[i][j], 0, 0, 0);
    }
  }

  __syncthreads();
  unsigned short* st = (unsigned short*)smem + wave * 4096;
  const int rq = (lane >> 4) * 4, cq = lane & 15;
#pragma unroll
  for (int i = 0; i < 4; ++i)
#pragma unroll
    for (int j = 0; j < 4; ++j)
#pragma unroll
      for (int p = 0; p < 4; ++p)
        EP_STORE(st, i * 16 + rq + p, j * 16 + cq, f2bf(acc[i][j][p]));
#pragma unroll
  for (int pass = 0; pass < 8; ++pass) {
    const int row = pass * 8 + (lane >> 3);
    u16x8 v = *(const u16x8*)(st + row * 64 + (((lane & 7) ^ (row & 7)) << 3));
    size_t off = (size_t)(tileM + wm + row) * 256 + tileN + wn + (lane & 7) * 8;
    *(u16x8*)(C + off) = v;
  }
}

// ------- layer 0 fused gather + mean + self + bias + ReLU + LN -> h (bf16) ---------
__global__ __launch_bounds__(256)
void k_gather0(const unsigned short* __restrict__ Y, const int2* __restrict__ scN,
               const int2* __restrict__ e2, const float* __restrict__ bias,
               const float* __restrict__ g, const float* __restrict__ bln,
               unsigned short* __restrict__ out) {
  const int wave = threadIdx.x >> 6, lane = threadIdx.x & 63;
  const int t = blockIdx.x * 4 + wave;
  if (t >= N_NODES) return;
  const int c0 = lane * 4;

  float a0, a1, a2, a3;
  {
    u16x4 sv = *(const u16x4*)(Y + (size_t)t * N_CAT + c0);
    f32x4 bb = *(const f32x4*)(bias + c0);
    a0 = bf2f(sv[0]) + bb[0];
    a1 = bf2f(sv[1]) + bb[1];
    a2 = bf2f(sv[2]) + bb[2];
    a3 = bf2f(sv[3]) + bb[3];
  }

  const int2 s = scN[t];                    // {start, padded_cnt (x4)}
  const int2* ep = e2 + s.x;
  for (int idx = 0; idx < s.y; idx += 4) {
    const int2 p0 = ep[idx + 0];
    const int2 p1 = ep[idx + 1];
    const int2 p2 = ep[idx + 2];
    const int2 p3 = ep[idx + 3];
    const unsigned short* y0 = Y + (size_t)(p0.x & 0xFFFF) * N_CAT + (((p0.x >> 16) + 1) << 8) + c0;
    const unsigned short* y1 = Y + (size_t)(p1.x & 0xFFFF) * N_CAT + (((p1.x >> 16) + 1) << 8) + c0;
    const unsigned short* y2 = Y + (size_t)(p2.x & 0xFFFF) * N_CAT + (((p2.x >> 16) + 1) << 8) + c0;
    const unsigned short* y3 = Y + (size_t)(p3.x & 0xFFFF) * N_CAT + (((p3.x >> 16) + 1) << 8) + c0;
    u16x4 v0 = *(const u16x4*)y0;
    u16x4 v1 = *(const u16x4*)y1;
    u16x4 v2 = *(const u16x4*)y2;
    u16x4 v3 = *(const u16x4*)y3;
    const float w0 = __int_as_float(p0.y), w1 = __int_as_float(p1.y);
    const float w2 = __int_as_float(p2.y), w3 = __int_as_float(p3.y);
    a0 += w0 * bf2f(v0[0]) + w1 * bf2f(v1[0]) + w2 * bf2f(v2[0]) + w3 * bf2f(v3[0]);
    a1 += w0 * bf2f(v0[1]) + w1 * bf2f(v1[1]) + w2 * bf2f(v2[1]) + w3 * bf2f(v3[1]);
    a2 += w0 * bf2f(v0[2]) + w1 * bf2f(v1[2]) + w2 * bf2f(v2[2]) + w3 * bf2f(v3[2]);
    a3 += w0 * bf2f(v0[3]) + w1 * bf2f(v1[3]) + w2 * bf2f(v2[3]) + w3 * bf2f(v3[3]);
  }

  a0 = fmaxf(a0, 0.f); a1 = fmaxf(a1, 0.f); a2 = fmaxf(a2, 0.f); a3 = fmaxf(a3, 0.f);

  float s1 = (a0 + a1) + (a2 + a3);
#pragma unroll
  for (int off = 32; off > 0; off >>= 1) s1 += __shfl_xor(s1, off, 64);
  const float mu = s1 * (1.f / 256.f);
  const float d0 = a0 - mu, d1 = a1 - mu, d2 = a2 - mu, d3 = a3 - mu;
  float s2 = (d0 * d0 + d1 * d1) + (d2 * d2 + d3 * d3);
#pragma unroll
  for (int off = 32; off > 0; off >>= 1) s2 += __shfl_xor(s2, off, 64);
  const float rs = rsqrtf(s2 * (1.f / 256.f) + LN_EPS);

  f32x4 gg = *(const f32x4*)(g + c0);
  f32x4 ll = *(const f32x4*)(bln + c0);
  u16x4 o = { f2bf(d0 * rs * gg[0] + ll[0]), f2bf(d1 * rs * gg[1] + ll[1]),
              f2bf(d2 * rs * gg[2] + ll[2]), f2bf(d3 * rs * gg[3] + ll[3]) };
  *(u16x4*)(out + (size_t)t * 256 + c0) = o;
}

// ------- layer 1 pre-GEMM gather: G8[t, r*256+c] = sum_w h[s][c]  (h cache-resident) --
__global__ __launch_bounds__(256)
void k_gatherG(const unsigned short* __restrict__ h, const int2* __restrict__ sc8,
               const int2* __restrict__ e2, unsigned short* __restrict__ G8) {
  const int wave = threadIdx.x >> 6, lane = threadIdx.x & 63;
  const int id = blockIdx.x * 4 + wave;          // (t<<3)|r
  if (id >= N_NODES * 8) return;
  const int t = id >> 3, r = id & 7;
  const int c0 = lane * 4;
  const int2 s = sc8[id];                        // {global start, cnt}
  float a0 = 0, a1 = 0, a2 = 0, a3 = 0;
  for (int i = 0; i < s.y; ++i) {
    const int2 p = e2[s.x + i];
    const float w = __int_as_float(p.y);
    u16x4 v = *(const u16x4*)(h + (size_t)(p.x & 0xFFFF) * 256 + c0);
    a0 += w * bf2f(v[0]); a1 += w * bf2f(v[1]);
    a2 += w * bf2f(v[2]); a3 += w * bf2f(v[3]);
  }
  u16x4 o = { f2bf(a0), f2bf(a1), f2bf(a2), f2bf(a3) };
  *(u16x4*)(G8 + (size_t)t * 2048 + r * 256 + c0) = o;
}

// ------- final bias + ReLU + LN: Ypre (bf16) -> d_out (f32) --------------------------
__global__ __launch_bounds__(256)
void k_ln(const unsigned short* __restrict__ Ypre, const float* __restrict__ bias,
          const float* __restrict__ g, const float* __restrict__ bln,
          float* __restrict__ out) {
  const int wave = threadIdx.x >> 6, lane = threadIdx.x & 63;
  const int t = blockIdx.x * 4 + wave;
  if (t >= N_NODES) return;
  const int c0 = lane * 4;
  u16x4 sv = *(const u16x4*)(Ypre + (size_t)t * 256 + c0);
  f32x4 bb = *(const f32x4*)(bias + c0);
  float a0 = fmaxf(bf2f(sv[0]) + bb[0], 0.f);
  float a1 = fmaxf(bf2f(sv[1]) + bb[1], 0.f);
  float a2 = fmaxf(bf2f(sv[2]) + bb[2], 0.f);
  float a3 = fmaxf(bf2f(sv[3]) + bb[3], 0.f);
  float s1 = (a0 + a1) + (a2 + a3);
#pragma unroll
  for (int off = 32; off > 0; off >>= 1) s1 += __shfl_xor(s1, off, 64);
  const float mu = s1 * (1.f / 256.f);
  const float d0 = a0 - mu, d1 = a1 - mu, d2 = a2 - mu, d3 = a3 - mu;
  float s2 = (d0 * d0 + d1 * d1) + (d2 * d2 + d3 * d3);
#pragma unroll
  for (int off = 32; off > 0; off >>= 1) s2 += __shfl_xor(s2, off, 64);
  const float rs = rsqrtf(s2 * (1.f / 256.f) + LN_EPS);
  f32x4 gg = *(const f32x4*)(g + c0);
  f32x4 ll = *(const f32x4*)(bln + c0);
  f32x4 o = { d0 * rs * gg[0] + ll[0], d1 * rs * gg[1] + ll[1],
              d2 * rs * gg[2] + ll[2], d3 * rs * gg[3] + ll[3] };
  *(f32x4*)(out + (size_t)t * 256 + c0) = o;
}

// ---------------- launch ----------------
extern "C" void kernel_launch(void* const* d_in, const int* in_sizes, int n_in,
                              void* d_out, int out_size, void* d_ws, size_t ws_size,
                              hipStream_t stream) {
  (void)in_sizes; (void)n_in; (void)out_size; (void)ws_size;
  const float* x   = (const float*)d_in[0];
  const float* nw  = (const float*)d_in[1];
  const int*   esrc = (const int*)d_in[2];
  const int*   etgt = (const int*)d_in[3];
  const float* Wr0 = (const float*)d_in[4];
  const float* Ws0 = (const float*)d_in[5];
  const float* Wb0 = (const float*)d_in[6];
  const float* g0  = (const float*)d_in[7];
  const float* b0  = (const float*)d_in[8];
  const float* Wr1 = (const float*)d_in[9];
  const float* Ws1 = (const float*)d_in[10];
  const float* Wb1 = (const float*)d_in[11];
  const float* g1  = (const float*)d_in[12];
  const float* b1  = (const float*)d_in[13];

  char* p = (char*)d_ws;
  auto carve = [&](size_t bytes) {
    char* q = p;
    p += (bytes + 511) & ~(size_t)511;
    return q;
  };
  unsigned short* Y    = (unsigned short*)carve((size_t)M_PAD * N_CAT * 2);  // 230.6 MB
  unsigned short* G8   = Y;    // layer-1 gathered means [M_PAD,2048] alias dead Y
  unsigned short* xb   = (unsigned short*)carve((size_t)M_PAD * D_IN * 2);   //  76.9 MB
  unsigned short* h    = (unsigned short*)carve((size_t)M_PAD * 256 * 2);    //  25.6 MB
  unsigned short* Ypre = (unsigned short*)carve((size_t)M_PAD * 256 * 2);    //  25.6 MB
  unsigned short* Wt0  = (unsigned short*)carve((size_t)N_CAT * D_IN * 2);
  unsigned short* Wt1b = (unsigned short*)carve((size_t)256 * K1 * 2);
  int*   deg     = (int*)carve((size_t)R_REL * N_NODES * 4);
  int*   pdeg    = (int*)carve((size_t)N_NODES * 4);
  int*   cursor8 = (int*)carve((size_t)N_NODES * 8 * 4);
  int*   nodeptr = (int*)carve((size_t)(N_NODES + 1) * 4);
  int*   bsum    = (int*)carve((size_t)NCHUNK * 4);
  int*   chunkoff= (int*)carve((size_t)NCHUNK * 4);
  int2*  e2      = (int2*)carve((size_t)E_PAD_MAX * 8);
  int2*  scN     = (int2*)carve((size_t)N_NODES * 8);
  int2*  sc8     = (int2*)carve((size_t)N_NODES * 8 * 8);

  // CSR build (node-major, rel-grouped; shared by both layers)
  hipMemsetAsync(deg, 0, (size_t)R_REL * N_NODES * 4, stream);
  hipMemsetAsync(cursor8, 0, (size_t)N_NODES * 8 * 4, stream);
  hipMemsetAsync(e2, 0, (size_t)E_PAD_MAX * 8, stream);   // pad slots -> {src0,rel0,w=0}
  k_deg<<<(R_REL * E_EDGES + 255) / 256, 256, 0, stream>>>(etgt, deg);
  k_ndeg<<<(N_NODES + 255) / 256, 256, 0, stream>>>(deg, pdeg);
  k_scan1<<<NCHUNK, 256, 0, stream>>>(pdeg, nodeptr, bsum);
  k_scan2<<<1, 64, 0, stream>>>(bsum, chunkoff, nodeptr);
  k_scan3<<<NCHUNK, 256, 0, stream>>>(chunkoff, nodeptr);
  k_prep<<<(N_NODES + 255) / 256, 256, 0, stream>>>(nodeptr, scN);
  k_prep8<<<(N_NODES * 8 + 255) / 256, 256, 0, stream>>>(nodeptr, deg, sc8);
  k_fill<<<(R_REL * E_EDGES + 255) / 256, 256, 0, stream>>>(esrc, etgt, nw, sc8,
                                                            deg, cursor8, e2);
  // conversions
  k_cvt_x<<<(N_NODES * D_IN / 4 + 255) / 256, 256, 0, stream>>>(x, xb);
  k_cvt_w<<<(N_CAT * D_IN + 255) / 256, 256, 0, stream>>>(Ws0, Wr0, Wt0, D_IN);
  k_cvt_w1<<<(256 * K1 + 255) / 256, 256, 0, stream>>>(Ws1, Wr1, Wt1b);

  // layer 0: big GEMM -> Y, then fused gather+LN -> h
  k_gemm<<<8 * ((18 * TILES_M + 7) / 8), 256, 0, stream>>>(xb, Wt0, Y, D_IN);
  k_gather0<<<(N_NODES + 3) / 4, 256, 0, stream>>>(Y, scN, e2, Wb0, g0, b0, h);
  // layer 1: gather means in h-space (cache-resident) -> G8 (aliases Y), then GEMM+LN
  k_gatherG<<<(N_NODES * 8 + 3) / 4, 256, 0, stream>>>(h, sc8, e2, G8);
  k_gemm2<<<8 * ((2 * TILES_M + 7) / 8), 256, 0, stream>>>(h, G8, Wt1b, Ypre);
  k_ln<<<(N_NODES + 3) / 4, 256, 0, stream>>>(Ypre, Wb1, g1, b1, (float*)d_out);
}